// Round 10
// baseline (502.404 us; speedup 1.0000x reference)
//
#include <hip/hip_runtime.h>

#define NFEAT 128
#define DOUT 48
#define OSPLIT 4              // 4 threads per node, 12 outputs each
#define OPT (DOUT / OSPLIT)   // 12
#define BSH 6                 // 64 nodes per bucket
#define BNODES 64
#define PCAP 192              // capacity per (bucket,class): mean 128, sigma 11.3
#define BCAP (PCAP * 8)       // 1536 entries per bucket
#define EPT 16                // edges per thread in k_bin (4096/block, 391 blocks)
#define NBMAX 1568            // LDS histogram size (>= NB=1563)

__device__ __forceinline__ float bf_lo(unsigned u) { return __uint_as_float(u << 16); }
__device__ __forceinline__ float bf_hi(unsigned u) { return __uint_as_float(u & 0xFFFF0000u); }
__device__ __forceinline__ unsigned bf_pack(float a, float b) {
    unsigned ua = __float_as_uint(a), ub = __float_as_uint(b);
    ua = (ua + 0x7FFFu + ((ua >> 16) & 1u)) >> 16;          // RN-even
    ub = (ub + 0x7FFFu + ((ub >> 16) & 1u)) & 0xFFFF0000u;
    return ua | ub;
}

// ---------------- kernel A: h = feat @ W^T + b (bf16-packed); 4 threads per node ----------------
// Each thread computes 12 of 48 outputs -> grid x4 (1563 blocks, ~6 waves/SIMD) to fix the
// 17%-occupancy latency stall of the 1-thread-per-node version.
__global__ __launch_bounds__(256) void k_proj(
    const float* __restrict__ feat, const float* __restrict__ Ww,
    const float* __restrict__ Wb, const float* __restrict__ attn_w,
    unsigned* __restrict__ hbf, float* __restrict__ s_src, float* __restrict__ s_dst,
    int n)
{
    int t = blockIdx.x * 256 + threadIdx.x;
    int node = t >> 2;
    int part = t & 3;                 // lanes {4k..4k+3} share a node
    if (node >= n) return;
    int jbase = part * OPT;

    float hv[OPT];
#pragma unroll
    for (int j = 0; j < OPT; ++j) hv[j] = Wb[jbase + j];

    const float4* fp = (const float4*)(feat + (size_t)node * NFEAT);
#pragma unroll 1
    for (int c = 0; c < 4; ++c) {
        float4 f[8];
#pragma unroll
        for (int i = 0; i < 8; ++i) f[i] = fp[c * 8 + i];    // 4 lanes same addr -> broadcast
#pragma unroll
        for (int j = 0; j < OPT; ++j) {                      // static indexing -> hv in VGPRs
            const float4* wp = (const float4*)(Ww + (size_t)(jbase + j) * NFEAT + c * 32);
            float acc = hv[j];
#pragma unroll
            for (int i = 0; i < 8; ++i) {
                float4 w = wp[i];                            // L1-resident (W = 24.6 KB)
                acc = fmaf(f[i].x, w.x, acc);
                acc = fmaf(f[i].y, w.y, acc);
                acc = fmaf(f[i].z, w.z, acc);
                acc = fmaf(f[i].w, w.w, acc);
            }
            hv[j] = acc;
        }
    }

    // partial attention dots over this thread's 12 outputs, reduced across the 4-lane group
    float ss = 0.f, sd = 0.f;
#pragma unroll
    for (int j = 0; j < OPT; ++j) {
        ss = fmaf(hv[j], attn_w[jbase + j], ss);
        sd = fmaf(hv[j], attn_w[DOUT + jbase + j], sd);
    }
    ss += __shfl_xor(ss, 1, 64); ss += __shfl_xor(ss, 2, 64);
    sd += __shfl_xor(sd, 1, 64); sd += __shfl_xor(sd, 2, 64);

    // pack 12 floats -> 6 uints (bf16 pairs), 3x uint2 stores at 24B offset (8B-aligned)
    uint2* hp = (uint2*)(hbf + (size_t)node * 24 + part * 6);
#pragma unroll
    for (int q = 0; q < 3; ++q) {
        uint2 v;
        v.x = bf_pack(hv[4 * q + 0], hv[4 * q + 1]);
        v.y = bf_pack(hv[4 * q + 2], hv[4 * q + 3]);
        hp[q] = v;
    }
    if (part == 0) {
        s_src[node] = ss;
        s_dst[node] = sd;
    }
}

// ---------------- bin edges: block-aggregated cursors ----------------
// 4096 edges/block. LDS histogram gives each edge its intra-block rank; ONE global
// atomicAdd per distinct bucket per block (~1450 vs 4096) claims the (bucket,cls) range.
__global__ __launch_bounds__(256) void k_bin(
    const int4* __restrict__ src4, const int4* __restrict__ dst4,
    const float* __restrict__ s_src, const float* __restrict__ s_dst,
    const float* __restrict__ attn_b,
    int* __restrict__ cursor, int2* __restrict__ ents, int nE, int NB)
{
    __shared__ int hist[NBMAX];
    __shared__ int bas[NBMAX];

    int tid = threadIdx.x;
    int cls = blockIdx.x & 7;
    long long e0 = (long long)blockIdx.x * 4096 + (long long)tid * EPT;

    for (int t = tid; t < NB; t += 256) hist[t] = 0;
    __syncthreads();

    int s[EPT], d[EPT];
    bool any = (e0 < nE);
#pragma unroll
    for (int q = 0; q < EPT / 4; ++q) {
        int4 sv = any ? src4[e0 / 4 + q] : make_int4(0, 0, 0, 0);
        int4 dv = any ? dst4[e0 / 4 + q] : make_int4(0, 0, 0, 0);
        s[4 * q + 0] = sv.x; s[4 * q + 1] = sv.y; s[4 * q + 2] = sv.z; s[4 * q + 3] = sv.w;
        d[4 * q + 0] = dv.x; d[4 * q + 1] = dv.y; d[4 * q + 2] = dv.z; d[4 * q + 3] = dv.w;
    }

    float vs[EPT], vd[EPT];
#pragma unroll
    for (int u = 0; u < EPT; ++u) vs[u] = s_src[s[u]];
#pragma unroll
    for (int u = 0; u < EPT; ++u) vd[u] = s_dst[d[u]];

    int rank[EPT];
#pragma unroll
    for (int u = 0; u < EPT; ++u)
        rank[u] = (e0 + u < nE) ? atomicAdd(&hist[d[u] >> BSH], 1) : 0;
    __syncthreads();

    for (int t = tid; t < NB; t += 256) {
        int c = hist[t];
        if (c > 0) bas[t] = atomicAdd(cursor + cls * NB + t, c);
    }
    __syncthreads();

    float ab = attn_b[0];
#pragma unroll
    for (int u = 0; u < EPT; ++u) {
        if (e0 + u < nE) {
            float v = vs[u] + vd[u] + ab;
            v = (v > 0.f) ? v : 0.2f * v;                    // leaky_relu(0.2)
            float x = __expf(v);                             // softmax shift-invariant
            int bkt = d[u] >> BSH;
            int slot = bas[bkt] + rank[u];
            if (slot < PCAP)
                ents[(size_t)bkt * BCAP + cls * PCAP + slot] =
                    make_int2(s[u] | ((d[u] & (BNODES - 1)) << 17), __float_as_int(x));
        }
    }
}

// ---------------- fused LDS-sort + softmax-aggregate: one block per bucket ----------------
__global__ __launch_bounds__(256) void k_aggb(
    const unsigned* __restrict__ hbf, const int* __restrict__ cursor,
    const int2* __restrict__ ents, float* __restrict__ out, int n, int NB)
{
    __shared__ int2 se[BCAP];
    __shared__ unsigned short sidx[BCAP];
    __shared__ int c1[BNODES], c2[BNODES], lrp[BNODES + 1];
    __shared__ int cp[9];

    int b = blockIdx.x;
    int tid = threadIdx.x;

    if (tid < BNODES) { c1[tid] = 0; c2[tid] = 0; }
    __syncthreads();
    if (tid == 0) {
        int r = 0;
        for (int c = 0; c < 8; ++c) {
            cp[c] = r;
            r += min(cursor[c * NB + b], PCAP);              // class-major cursor layout
        }
        cp[8] = r;
    }
    __syncthreads();
    int total = cp[8];

    for (int i = tid; i < total; i += 256) {
        int c = 0;
        while (i >= cp[c + 1]) ++c;                          // <=8 iters
        int2 v = ents[(size_t)b * BCAP + c * PCAP + (i - cp[c])];
        se[i] = v;
        atomicAdd(&c1[((unsigned)v.x) >> 17], 1);
    }
    __syncthreads();

    if (tid < BNODES) {
        int v = c1[tid];
        int p = v;
#pragma unroll
        for (int o = 1; o < 64; o <<= 1) {
            int u = __shfl_up(p, o, 64);
            if (tid >= o) p += u;
        }
        lrp[tid] = p - v;
        if (tid == BNODES - 1) lrp[BNODES] = p;
    }
    __syncthreads();

    for (int i = tid; i < total; i += 256) {
        int dl = ((unsigned)se[i].x) >> 17;
        int pos = lrp[dl] + atomicAdd(&c2[dl], 1);
        sidx[pos] = (unsigned short)i;
    }
    __syncthreads();

    int wave = tid >> 6, lane = tid & 63;
    int g = lane >> 3, sub = lane & 7;
    for (int dl = wave; dl < BNODES; dl += 4) {
        int node = (b << BSH) + dl;
        if (node >= n) break;
        int st = lrp[dl], en = lrp[dl + 1];
        float a0 = 0.f, a1 = 0.f, a2 = 0.f, a3 = 0.f, a4 = 0.f, a5 = 0.f, den = 0.f;
        for (int k = st + g; k < en; k += 8) {
            int2 ed = se[sidx[k]];                           // LDS broadcast across 8 lanes
            float x = __int_as_float(ed.y);
            den += x;
            const unsigned* hr = hbf + (size_t)(ed.x & 0x1FFFF) * 24 + sub * 3;
            unsigned u0 = hr[0], u1 = hr[1], u2 = hr[2];
            a0 = fmaf(x, bf_lo(u0), a0);
            a1 = fmaf(x, bf_hi(u0), a1);
            a2 = fmaf(x, bf_lo(u1), a2);
            a3 = fmaf(x, bf_hi(u1), a3);
            a4 = fmaf(x, bf_lo(u2), a4);
            a5 = fmaf(x, bf_hi(u2), a5);
        }
#pragma unroll
        for (int o = 8; o <= 32; o <<= 1) {                  // reduce across the 8 groups
            a0  += __shfl_xor(a0, o, 64);
            a1  += __shfl_xor(a1, o, 64);
            a2  += __shfl_xor(a2, o, 64);
            a3  += __shfl_xor(a3, o, 64);
            a4  += __shfl_xor(a4, o, 64);
            a5  += __shfl_xor(a5, o, 64);
            den += __shfl_xor(den, o, 64);
        }
        if (lane < 8) {
            float inv = (en > st) ? 1.f / den : 0.f;
            float* op = out + (size_t)node * DOUT + sub * 6;
            op[0] = a0 * inv;
            op[1] = a1 * inv;
            op[2] = a2 * inv;
            op[3] = a3 * inv;
            op[4] = a4 * inv;
            op[5] = a5 * inv;
        }
    }
}

extern "C" void kernel_launch(void* const* d_in, const int* in_sizes, int n_in,
                              void* d_out, int out_size, void* d_ws, size_t ws_size,
                              hipStream_t stream) {
    const float* feat   = (const float*)d_in[0];
    const float* Ww     = (const float*)d_in[1];
    const float* Wb     = (const float*)d_in[2];
    const float* attn_w = (const float*)d_in[3];
    const float* attn_b = (const float*)d_in[4];
    const int*   src    = (const int*)d_in[5];
    const int*   dst    = (const int*)d_in[6];

    int n  = in_sizes[0] / NFEAT;          // 100000
    int nE = in_sizes[5];                  // 1600000
    int NB = (n + BNODES - 1) / BNODES;    // 1563 buckets
    int N8 = NB * 8;                       // class-major cursors
    float* out = (float*)d_out;

    // workspace layout
    unsigned* hbf  = (unsigned*)d_ws;                 // n*24 uints (bf16-packed h, 96B/row)
    float* s_src   = (float*)(hbf + (size_t)n * 24);  // n
    float* s_dst   = s_src + n;                       // n
    int*   cursor  = (int*)(s_dst + n);               // N8
    int2*  ents    = (int2*)(cursor + N8);            // NB*BCAP

    hipMemsetAsync(cursor, 0, (size_t)N8 * sizeof(int), stream);

    k_proj<<<((n * OSPLIT) + 255) / 256, 256, 0, stream>>>(feat, Ww, Wb, attn_w,
                                                           hbf, s_src, s_dst, n);
    int nbb = (nE + 4095) / 4096;                     // 391 blocks, 4096 edges each
    k_bin<<<nbb, 256, 0, stream>>>((const int4*)src, (const int4*)dst,
                                   s_src, s_dst, attn_b, cursor, ents, nE, NB);
    k_aggb<<<NB, 256, 0, stream>>>(hbf, cursor, ents, out, n, NB);
}

// Round 11
// 202.525 us; speedup vs baseline: 2.4807x; 2.4807x over previous
//
#include <hip/hip_runtime.h>

#define NFEAT 128
#define DOUT 48
#define BSH 6                 // 64 nodes per bucket
#define BNODES 64
#define PCAP 192              // capacity per (bucket,class): mean 128, sigma 11.3
#define BCAP (PCAP * 8)       // 1536 entries per bucket
#define EPT 16                // edges per thread in k_bin (4096/block, 391 blocks)
#define NBMAX 1568            // LDS histogram size (>= NB=1563)

__device__ __forceinline__ float bf_lo(unsigned u) { return __uint_as_float(u << 16); }
__device__ __forceinline__ float bf_hi(unsigned u) { return __uint_as_float(u & 0xFFFF0000u); }
__device__ __forceinline__ unsigned bf_pack(float a, float b) {
    unsigned ua = __float_as_uint(a), ub = __float_as_uint(b);
    ua = (ua + 0x7FFFu + ((ua >> 16) & 1u)) >> 16;          // RN-even
    ub = (ub + 0x7FFFu + ((ub >> 16) & 1u)) & 0xFFFF0000u;
    return ua | ub;
}

// ---------------- kernel A: h = feat @ W^T + b (bf16-packed out) ----------------
// K-split across waves: block = 4 waves over the SAME 64 nodes; wave w does K-quarter w.
// kq is readfirstlane'd -> W pointer wave-uniform -> s_load bursts (SGPR W operands),
// the property round 10 accidentally destroyed (SGPR 112->32 = lost scalarization).
// LDS combine: waves 0/2 write bufA/bufB, waves 1/3 accumulate, epilogue sums A+B.
__global__ __launch_bounds__(256) void k_proj(
    const float* __restrict__ feat, const float* __restrict__ Ww,
    const float* __restrict__ Wb, const float* __restrict__ attn_w,
    unsigned* __restrict__ hbf, float* __restrict__ s_src, float* __restrict__ s_dst,
    int n)
{
    __shared__ float hbA[64][49];
    __shared__ float hbB[64][49];

    int tid  = threadIdx.x;
    int lane = tid & 63;
    int kq   = __builtin_amdgcn_readfirstlane(tid >> 6);   // wave id = K-quarter, SGPR
    int gnode = blockIdx.x * 64 + lane;
    bool live = (gnode < n);

    float hv[DOUT];
#pragma unroll
    for (int j = 0; j < DOUT; ++j) hv[j] = 0.f;

    if (live) {
        const float4* fp = (const float4*)(feat + (size_t)gnode * NFEAT + kq * 32);
        float4 f[8];
#pragma unroll
        for (int i = 0; i < 8; ++i) f[i] = fp[i];
#pragma unroll
        for (int j = 0; j < DOUT; ++j) {                   // static idx -> hv in VGPRs
            const float4* wp = (const float4*)(Ww + (size_t)j * NFEAT + kq * 32);  // uniform -> s_load
            float acc = hv[j];
#pragma unroll
            for (int i = 0; i < 8; ++i) {
                float4 w = wp[i];
                acc = fmaf(f[i].x, w.x, acc);
                acc = fmaf(f[i].y, w.y, acc);
                acc = fmaf(f[i].z, w.z, acc);
                acc = fmaf(f[i].w, w.w, acc);
            }
            hv[j] = acc;
        }
    }

    // combine: phase 0 (waves 0,2) write; phase 1 (waves 1,3) accumulate
    float (*hb)[49] = (kq < 2) ? hbA : hbB;
    if ((kq & 1) == 0) {
#pragma unroll
        for (int j = 0; j < DOUT; ++j) hb[lane][j] = hv[j];
    }
    __syncthreads();
    if ((kq & 1) == 1) {
#pragma unroll
        for (int j = 0; j < DOUT; ++j) hb[lane][j] += hv[j];
    }
    __syncthreads();

    // epilogue: 4 threads per node; thread covers 12 outputs; add bias here
    int node = tid >> 2, part = tid & 3, jb = part * 12;
    int gn2 = blockIdx.x * 64 + node;
    float v[12];
#pragma unroll
    for (int j = 0; j < 12; ++j) v[j] = hbA[node][jb + j] + hbB[node][jb + j] + Wb[jb + j];

    float ss = 0.f, sd = 0.f;
#pragma unroll
    for (int j = 0; j < 12; ++j) {
        ss = fmaf(v[j], attn_w[jb + j], ss);
        sd = fmaf(v[j], attn_w[DOUT + jb + j], sd);
    }
    ss += __shfl_xor(ss, 1, 64); ss += __shfl_xor(ss, 2, 64);
    sd += __shfl_xor(sd, 1, 64); sd += __shfl_xor(sd, 2, 64);

    if (gn2 < n) {
        uint2* hp = (uint2*)(hbf + (size_t)gn2 * 24 + part * 6);
#pragma unroll
        for (int q = 0; q < 3; ++q) {
            uint2 u;
            u.x = bf_pack(v[4 * q + 0], v[4 * q + 1]);
            u.y = bf_pack(v[4 * q + 2], v[4 * q + 3]);
            hp[q] = u;
        }
        if (part == 0) {
            s_src[gn2] = ss;
            s_dst[gn2] = sd;
        }
    }
}

// ---------------- bin edges: block-aggregated cursors ----------------
__global__ __launch_bounds__(256) void k_bin(
    const int4* __restrict__ src4, const int4* __restrict__ dst4,
    const float* __restrict__ s_src, const float* __restrict__ s_dst,
    const float* __restrict__ attn_b,
    int* __restrict__ cursor, int2* __restrict__ ents, int nE, int NB)
{
    __shared__ int hist[NBMAX];
    __shared__ int bas[NBMAX];

    int tid = threadIdx.x;
    int cls = blockIdx.x & 7;
    long long e0 = (long long)blockIdx.x * 4096 + (long long)tid * EPT;

    for (int t = tid; t < NB; t += 256) hist[t] = 0;
    __syncthreads();

    int s[EPT], d[EPT];
    bool any = (e0 < nE);
#pragma unroll
    for (int q = 0; q < EPT / 4; ++q) {
        int4 sv = any ? src4[e0 / 4 + q] : make_int4(0, 0, 0, 0);
        int4 dv = any ? dst4[e0 / 4 + q] : make_int4(0, 0, 0, 0);
        s[4 * q + 0] = sv.x; s[4 * q + 1] = sv.y; s[4 * q + 2] = sv.z; s[4 * q + 3] = sv.w;
        d[4 * q + 0] = dv.x; d[4 * q + 1] = dv.y; d[4 * q + 2] = dv.z; d[4 * q + 3] = dv.w;
    }

    float vs[EPT], vd[EPT];
#pragma unroll
    for (int u = 0; u < EPT; ++u) vs[u] = s_src[s[u]];
#pragma unroll
    for (int u = 0; u < EPT; ++u) vd[u] = s_dst[d[u]];

    int rank[EPT];
#pragma unroll
    for (int u = 0; u < EPT; ++u)
        rank[u] = (e0 + u < nE) ? atomicAdd(&hist[d[u] >> BSH], 1) : 0;
    __syncthreads();

    for (int t = tid; t < NB; t += 256) {
        int c = hist[t];
        if (c > 0) bas[t] = atomicAdd(cursor + cls * NB + t, c);
    }
    __syncthreads();

    float ab = attn_b[0];
#pragma unroll
    for (int u = 0; u < EPT; ++u) {
        if (e0 + u < nE) {
            float v = vs[u] + vd[u] + ab;
            v = (v > 0.f) ? v : 0.2f * v;                    // leaky_relu(0.2)
            float x = __expf(v);                             // softmax shift-invariant
            int bkt = d[u] >> BSH;
            int slot = bas[bkt] + rank[u];
            if (slot < PCAP)
                ents[(size_t)bkt * BCAP + cls * PCAP + slot] =
                    make_int2(s[u] | ((d[u] & (BNODES - 1)) << 17), __float_as_int(x));
        }
    }
}

// ---------------- fused LDS-sort + softmax-aggregate: one block per bucket ----------------
__global__ __launch_bounds__(256) void k_aggb(
    const unsigned* __restrict__ hbf, const int* __restrict__ cursor,
    const int2* __restrict__ ents, float* __restrict__ out, int n, int NB)
{
    __shared__ int2 se[BCAP];
    __shared__ unsigned short sidx[BCAP];
    __shared__ int c1[BNODES], c2[BNODES], lrp[BNODES + 1];
    __shared__ int cp[9];

    int b = blockIdx.x;
    int tid = threadIdx.x;

    if (tid < BNODES) { c1[tid] = 0; c2[tid] = 0; }
    __syncthreads();
    if (tid == 0) {
        int r = 0;
        for (int c = 0; c < 8; ++c) {
            cp[c] = r;
            r += min(cursor[c * NB + b], PCAP);              // class-major cursor layout
        }
        cp[8] = r;
    }
    __syncthreads();
    int total = cp[8];

    for (int i = tid; i < total; i += 256) {
        int c = 0;
        while (i >= cp[c + 1]) ++c;                          // <=8 iters
        int2 v = ents[(size_t)b * BCAP + c * PCAP + (i - cp[c])];
        se[i] = v;
        atomicAdd(&c1[((unsigned)v.x) >> 17], 1);
    }
    __syncthreads();

    if (tid < BNODES) {
        int v = c1[tid];
        int p = v;
#pragma unroll
        for (int o = 1; o < 64; o <<= 1) {
            int u = __shfl_up(p, o, 64);
            if (tid >= o) p += u;
        }
        lrp[tid] = p - v;
        if (tid == BNODES - 1) lrp[BNODES] = p;
    }
    __syncthreads();

    for (int i = tid; i < total; i += 256) {
        int dl = ((unsigned)se[i].x) >> 17;
        int pos = lrp[dl] + atomicAdd(&c2[dl], 1);
        sidx[pos] = (unsigned short)i;
    }
    __syncthreads();

    int wave = tid >> 6, lane = tid & 63;
    int g = lane >> 3, sub = lane & 7;
    for (int dl = wave; dl < BNODES; dl += 4) {
        int node = (b << BSH) + dl;
        if (node >= n) break;
        int st = lrp[dl], en = lrp[dl + 1];
        float a0 = 0.f, a1 = 0.f, a2 = 0.f, a3 = 0.f, a4 = 0.f, a5 = 0.f, den = 0.f;
        for (int k = st + g; k < en; k += 8) {
            int2 ed = se[sidx[k]];                           // LDS broadcast across 8 lanes
            float x = __int_as_float(ed.y);
            den += x;
            const unsigned* hr = hbf + (size_t)(ed.x & 0x1FFFF) * 24 + sub * 3;
            unsigned u0 = hr[0], u1 = hr[1], u2 = hr[2];
            a0 = fmaf(x, bf_lo(u0), a0);
            a1 = fmaf(x, bf_hi(u0), a1);
            a2 = fmaf(x, bf_lo(u1), a2);
            a3 = fmaf(x, bf_hi(u1), a3);
            a4 = fmaf(x, bf_lo(u2), a4);
            a5 = fmaf(x, bf_hi(u2), a5);
        }
#pragma unroll
        for (int o = 8; o <= 32; o <<= 1) {                  // reduce across the 8 groups
            a0  += __shfl_xor(a0, o, 64);
            a1  += __shfl_xor(a1, o, 64);
            a2  += __shfl_xor(a2, o, 64);
            a3  += __shfl_xor(a3, o, 64);
            a4  += __shfl_xor(a4, o, 64);
            a5  += __shfl_xor(a5, o, 64);
            den += __shfl_xor(den, o, 64);
        }
        if (lane < 8) {
            float inv = (en > st) ? 1.f / den : 0.f;
            float* op = out + (size_t)node * DOUT + sub * 6;
            op[0] = a0 * inv;
            op[1] = a1 * inv;
            op[2] = a2 * inv;
            op[3] = a3 * inv;
            op[4] = a4 * inv;
            op[5] = a5 * inv;
        }
    }
}

extern "C" void kernel_launch(void* const* d_in, const int* in_sizes, int n_in,
                              void* d_out, int out_size, void* d_ws, size_t ws_size,
                              hipStream_t stream) {
    const float* feat   = (const float*)d_in[0];
    const float* Ww     = (const float*)d_in[1];
    const float* Wb     = (const float*)d_in[2];
    const float* attn_w = (const float*)d_in[3];
    const float* attn_b = (const float*)d_in[4];
    const int*   src    = (const int*)d_in[5];
    const int*   dst    = (const int*)d_in[6];

    int n  = in_sizes[0] / NFEAT;          // 100000
    int nE = in_sizes[5];                  // 1600000
    int NB = (n + BNODES - 1) / BNODES;    // 1563 buckets
    int N8 = NB * 8;                       // class-major cursors
    float* out = (float*)d_out;

    // workspace layout
    unsigned* hbf  = (unsigned*)d_ws;                 // n*24 uints (bf16-packed h, 96B/row)
    float* s_src   = (float*)(hbf + (size_t)n * 24);  // n
    float* s_dst   = s_src + n;                       // n
    int*   cursor  = (int*)(s_dst + n);               // N8
    int2*  ents    = (int2*)(cursor + N8);            // NB*BCAP

    hipMemsetAsync(cursor, 0, (size_t)N8 * sizeof(int), stream);

    k_proj<<<NB, 256, 0, stream>>>(feat, Ww, Wb, attn_w, hbf, s_src, s_dst, n);
    int nbb = (nE + 4095) / 4096;                     // 391 blocks, 4096 edges each
    k_bin<<<nbb, 256, 0, stream>>>((const int4*)src, (const int4*)dst,
                                   s_src, s_dst, attn_b, cursor, ents, nE, NB);
    k_aggb<<<NB, 256, 0, stream>>>(hbf, cursor, ents, out, n, NB);
}